// Round 1
// baseline (273.029 us; speedup 1.0000x reference)
//
#include <hip/hip_runtime.h>
#include <stdint.h>
#include <math.h>

#define N_CLS    81
#define TOPK     1000
#define LISTCAP  (1u << 21)     // 2M candidate keys (16 MB)
#define CAP2     16384          // final selection capacity
#define SCORE_TH 0.05f
#define IMG_W    1333.0f
#define IMG_H    800.0f
#define GH_REP   8              // coarse-hist replicas (atomic spread)

// coarse bucket = float_bits >> 19, range for (0.05, 1.0] is [1961, 2032]
#define GH_BASE  1905           // ghist index = (bits>>19) - GH_BASE, in [56,127]

// workspace layout (byte offsets)
#define OFF_CNT    0                       // u32 total candidates
#define OFF_CNT2   8                       // u32 selected count
#define OFF_GH     64                      // u32[GH_REP][128] coarse hist (4096 B)
#define OFF_RH     4608                    // u32[1024] refined hist (4096 B)
#define OFF_SORTED 8704                    // u64[1000] sorted keys (0 sentinel)
#define MEMSET_BYTES 16704
#define OFF_SEL    16768                   // u64[LISTCAP]
#define OFF_SEL2   16793984                // u64[CAP2]
#define OFF_BOX    16925056                // f32[1000*4]
#define OFF_SCORE  16941056                // f32[1000]
#define OFF_CLS    16945056                // i32[1000]
#define OFF_MASK   16949056                // u64[1000*16] conflict bit matrix

typedef unsigned long long u64;

// ------- K1: thread-per-row softmax + threshold + compact -------
// Replaces the wave-per-4-rows shuffle version: zero cross-lane ops.
// Summation reproduces the EXACT fp association of the old xor-butterfly
// (leaves t_l = e_l + e_{l+64}, pairwise tree over bit-reversed leaf order),
// so scores stay bit-identical to the verified kernel / JAX reference.
__global__ __launch_bounds__(256) void k_pass1(
        const float* __restrict__ logits, int nrows,
        u64* __restrict__ sel, unsigned* __restrict__ cnt,
        unsigned* __restrict__ ghist) {
    __shared__ unsigned lh[128];
    __shared__ u64 cbuf[2048];
    __shared__ unsigned lcnt, gbase;
    int tid = threadIdx.x;
    for (int i = tid; i < 128; i += 256) lh[i] = 0;
    if (tid == 0) lcnt = 0;
    __syncthreads();

    int row = blockIdx.x * 256 + tid;
    if (row < nrows) {
        const float* rp = logits + (size_t)row * N_CLS;

        // ---- pass A: row max (order-free, 4 ILP chains) ----
        float m0 = rp[0], m1 = rp[1], m2 = rp[2], m3 = rp[3];
        for (int j = 4; j + 3 < N_CLS; j += 4) {
            m0 = fmaxf(m0, rp[j]);
            m1 = fmaxf(m1, rp[j + 1]);
            m2 = fmaxf(m2, rp[j + 2]);
            m3 = fmaxf(m3, rp[j + 3]);
        }
        m0 = fmaxf(m0, rp[N_CLS - 1]);
        float m = fmaxf(fmaxf(m0, m1), fmaxf(m2, m3));

        // ---- pass B: sum of exps with the exact old tree association ----
        // old: s_l = e_l + e_{l+64} (l<17) else e_l; then xor-reduce offsets
        // 32,16,8,4,2,1. Equivalent: pairwise tree over leaves in
        // bit-reversed(6) order, streamed via a binary-counter stack.
        float stk0 = 0.f, stk1 = 0.f, stk2 = 0.f, stk3 = 0.f, stk4 = 0.f, stk5 = 0.f;
        float s = 0.f;
        #pragma unroll
        for (int i = 0; i < 64; i++) {
            const int l = ((i & 1) << 5) | ((i & 2) << 3) | ((i & 4) << 1) |
                          ((i & 8) >> 1) | ((i & 16) >> 3) | ((i & 32) >> 5); // bitrev6(i)
            float x = expf(rp[l] - m);
            if (l < 17) x += expf(rp[l + 64] - m);
            if (i & 1) { x = stk0 + x;
              if (i & 2) { x = stk1 + x;
                if (i & 4) { x = stk2 + x;
                  if (i & 8) { x = stk3 + x;
                    if (i & 16) { x = stk4 + x;
                      if (i & 32) { s = stk5 + x; } else stk5 = x;
                    } else stk4 = x;
                  } else stk3 = x;
                } else stk2 = x;
              } else stk1 = x;
            } else stk0 = x;
        }

        // ---- pass C: emit candidates ----
        // conservative log-space pre-filter: any p=fl(e/s)>0.05 has
        // e > 0.0499999*s  =>  v-m > ln(0.049*s) with ~2% slack vs ~1e-7
        // rounding error. Survivors get the bit-exact p>0.05 test.
        float thr = m + logf(0.049f * s);
        unsigned rbase = (unsigned)row * N_CLS;
        for (int j = 1; j < N_CLS; j++) {      // class 0 (background) excluded
            float v = rp[j];
            if (v > thr) {
                float e = expf(v - m);
                float p = e / s;               // exact same div as before
                if (p > SCORE_TH) {
                    unsigned fb = __float_as_uint(p);
                    atomicAdd(&lh[(fb >> 19) - GH_BASE], 1u);
                    u64 key = ((u64)fb << 32) | (u64)(0xFFFFFFu - (rbase + (unsigned)j));
                    unsigned pos = atomicAdd(&lcnt, 1u);
                    if (pos < 2048) cbuf[pos] = key;
                    else { unsigned gp = atomicAdd(cnt, 1u); if (gp < LISTCAP) sel[gp] = key; }
                }
            }
        }
    }
    __syncthreads();
    unsigned* gh = ghist + (blockIdx.x & (GH_REP - 1)) * 128;
    for (int i = tid; i < 128; i += 256) {
        unsigned v = lh[i];
        if (v) atomicAdd(&gh[i], v);
    }
    unsigned total = lcnt; if (total > 2048u) total = 2048u;
    if (tid == 0) gbase = atomicAdd(cnt, total);
    __syncthreads();
    unsigned gb = gbase;
    for (unsigned i = tid; i < total; i += 256) {
        unsigned gp = gb + i;
        if (gp < LISTCAP) sel[gp] = cbuf[i];
    }
}

// find coarse bucket B (ghist idx) containing rank TOPK; returns -1 if total<TOPK.
// *c_above = count strictly above bucket B.
__device__ inline int scan_coarse(const unsigned* __restrict__ ghist, unsigned* c_above) {
    unsigned cum = 0;
    for (int i = 127; i >= 0; --i) {
        unsigned c = 0;
        #pragma unroll
        for (int r = 0; r < GH_REP; r++) c += ghist[r * 128 + i];
        if (cum + c >= TOPK) { *c_above = cum; return i; }
        cum += c;
    }
    *c_above = cum;
    return -1;
}

// ------- K2: refined 1024-bin hist (shift 9) inside the coarse bucket -------
__global__ __launch_bounds__(256) void k_refine(
        const u64* __restrict__ sel, const unsigned* __restrict__ cnt,
        const unsigned* __restrict__ ghist, unsigned* __restrict__ rhist) {
    __shared__ unsigned lh[1024];
    __shared__ int sB;
    int tid = threadIdx.x;
    for (int i = tid; i < 1024; i += 256) lh[i] = 0;
    if (tid == 0) { unsigned ca; sB = scan_coarse(ghist, &ca); }
    __syncthreads();
    int B = sB;
    if (B < 0) return;   // fewer than TOPK candidates total
    unsigned Bbits = (unsigned)(B + GH_BASE);
    unsigned M = *cnt; if (M > LISTCAP) M = LISTCAP;
    unsigned stride = gridDim.x * blockDim.x;
    for (unsigned i = blockIdx.x * blockDim.x + tid; i < M; i += stride) {
        unsigned bits = (unsigned)(sel[i] >> 32);
        if ((bits >> 19) == Bbits) atomicAdd(&lh[(bits >> 9) & 1023u], 1u);
    }
    __syncthreads();
    for (int i = tid; i < 1024; i += 256) {
        unsigned v = lh[i];
        if (v) atomicAdd(&rhist[i], v);
    }
}

// ------- K3: compute exact threshold tb, compact keys >= tb into sel2 -------
__global__ __launch_bounds__(256) void k_select(
        const u64* __restrict__ sel, const unsigned* __restrict__ cnt,
        const unsigned* __restrict__ ghist, const unsigned* __restrict__ rhist,
        u64* __restrict__ sel2, unsigned* __restrict__ cnt2) {
    __shared__ unsigned s4[256];
    __shared__ unsigned tbs;
    int tid = threadIdx.x, ln = tid & 63;
    unsigned ps = 0;
    #pragma unroll
    for (int k = 0; k < 4; k++) ps += rhist[tid * 4 + k];
    s4[tid] = ps;
    __syncthreads();
    if (tid == 0) {
        unsigned c_above;
        int B = scan_coarse(ghist, &c_above);
        unsigned tb = 0;
        if (B >= 0) {
            unsigned cab = c_above;
            int g = -1;
            for (int i = 255; i >= 0; --i) {
                if (cab + s4[i] >= TOPK) { g = i; break; }
                cab += s4[i];
            }
            int sb = 0;
            if (g >= 0) {
                for (int i = g * 4 + 3; i >= g * 4; --i) {
                    unsigned c = rhist[i];
                    if (cab + c >= TOPK) { sb = i; break; }
                    cab += c;
                }
            }
            tb = ((unsigned)(B + GH_BASE) << 19) | ((unsigned)sb << 9);
        }
        tbs = tb;
    }
    __syncthreads();
    unsigned tb = tbs;
    unsigned M = *cnt; if (M > LISTCAP) M = LISTCAP;
    unsigned stride = gridDim.x * blockDim.x;
    for (unsigned ibase = blockIdx.x * blockDim.x; ibase < M; ibase += stride) {
        unsigned i = ibase + tid;
        bool act = (i < M);
        u64 key = act ? sel[i] : 0ull;
        bool c = act && ((unsigned)(key >> 32) >= tb);
        u64 b = __ballot(c);
        int n = __popcll(b);
        if (n == 0) continue;
        unsigned wb = 0;
        if (ln == 0) wb = atomicAdd(cnt2, (unsigned)n);
        wb = __shfl(wb, 0);
        if (c) {
            unsigned pos = wb + (unsigned)__popcll(b & ((1ull << ln) - 1ull));
            if (pos < CAP2) sel2[pos] = key;
        }
    }
}

// ------- K4: exact rank by counting (keys distinct), scatter to sorted -------
__global__ __launch_bounds__(256) void k_rank(
        const u64* __restrict__ sel2, const unsigned* __restrict__ cnt2,
        u64* __restrict__ sorted) {
    __shared__ u64 ch[2048];
    unsigned S = *cnt2; if (S > CAP2) S = CAP2;
    if (blockIdx.x * 256u >= S) return;
    unsigned t = blockIdx.x * 256u + threadIdx.x;
    u64 my = (t < S) ? sel2[t] : 0ull;
    int r = 0;
    for (unsigned c0 = 0; c0 < S; c0 += 2048) {
        unsigned n = S - c0; if (n > 2048) n = 2048;
        __syncthreads();
        for (unsigned i = threadIdx.x; i < n; i += 256) ch[i] = sel2[c0 + i];
        __syncthreads();
        if (t < S)
            for (unsigned j = 0; j < n; j++) r += (ch[j] > my) ? 1 : 0;
    }
    if (t < S && r < TOPK) sorted[r] = my;
}

// ------- K5: decode keys, gather + clip boxes -------
__global__ __launch_bounds__(256) void k_decode(
        const u64* __restrict__ sorted, const float* __restrict__ boxes,
        float* __restrict__ boxK, float* __restrict__ scoreK, int* __restrict__ clsK) {
    int t = blockIdx.x * blockDim.x + threadIdx.x;
    if (t >= TOPK) return;
    u64 key = sorted[t];
    if (key != 0ull) {
        float sc = __uint_as_float((unsigned)(key >> 32));
        unsigned fi = 0xFFFFFFu - (unsigned)(key & 0xFFFFFFFFull);
        unsigned prop = fi / N_CLS;
        int cls = (int)(fi - prop * N_CLS);
        const float* b = boxes + (size_t)prop * 4;
        boxK[t * 4 + 0] = fminf(fmaxf(b[0], 0.0f), IMG_W - 1.0f);
        boxK[t * 4 + 1] = fminf(fmaxf(b[1], 0.0f), IMG_H - 1.0f);
        boxK[t * 4 + 2] = fminf(fmaxf(b[2], 0.0f), IMG_W - 1.0f);
        boxK[t * 4 + 3] = fminf(fmaxf(b[3], 0.0f), IMG_H - 1.0f);
        scoreK[t] = sc;
        clsK[t] = cls;
    } else {
        boxK[t * 4 + 0] = 0.0f; boxK[t * 4 + 1] = 0.0f;
        boxK[t * 4 + 2] = 0.0f; boxK[t * 4 + 3] = 0.0f;
        scoreK[t] = 0.0f;
        clsK[t] = -1;
    }
}

// ------- K6: conflict bit-matrix (IoU > 0.5 && same class) -------
__global__ __launch_bounds__(256) void k_conflict(
        const float* __restrict__ boxK, const int* __restrict__ clsK,
        u64* __restrict__ mask) {
    int t = blockIdx.x * blockDim.x + threadIdx.x;
    if (t >= TOPK * 16) return;
    int i = t >> 4, w = t & 15;
    float x1 = boxK[i * 4 + 0], y1 = boxK[i * 4 + 1];
    float x2 = boxK[i * 4 + 2], y2 = boxK[i * 4 + 3];
    int ci = clsK[i];
    float ai = (x2 - x1) * (y2 - y1);
    u64 m = 0;
    int jbase = w << 6;
    for (int jj = 0; jj < 64; jj++) {
        int j = jbase + jj;
        if (j >= TOPK) break;
        float u1 = boxK[j * 4 + 0], w1 = boxK[j * 4 + 1];
        float u2 = boxK[j * 4 + 2], w2 = boxK[j * 4 + 3];
        float aj = (u2 - u1) * (w2 - w1);
        float ww = fmaxf(fminf(x2, u2) - fmaxf(x1, u1), 0.0f);
        float hh = fmaxf(fminf(y2, w2) - fmaxf(y1, w1), 0.0f);
        float inter = ww * hh;
        float iou = inter / (ai + aj - inter + 1e-9f);
        if (iou > 0.5f && ci == clsK[j]) m |= (1ull << jj);
    }
    mask[(size_t)i * 16 + w] = m;
}

// ------- K7: Jacobi fixed-point of the triangular greedy-NMS recurrence -------
// keep[i] = valid[i] & !OR_{j<i}(keep[j] & conflict[j][i]); unique fixed point.
__global__ __launch_bounds__(1024) void k_nms_out(
        const u64* __restrict__ mask, const float* __restrict__ boxK,
        const float* __restrict__ scoreK, float* __restrict__ out) {
    __shared__ u64 words[16];
    __shared__ int changed;
    int tid = threadIdx.x, wv = tid >> 6, ln = tid & 63;
    bool valid = (tid < TOPK) && (scoreK[tid] > 0.0f);
    u64 row[16];
    #pragma unroll
    for (int w = 0; w < 16; w++)
        row[w] = (tid < TOPK) ? mask[(size_t)tid * 16 + w] : 0ull;
    u64 lowmask = (1ull << ln) - 1ull;
    bool keep = valid;
    for (int it = 0; it < 1024; ++it) {
        u64 b = __ballot(keep);
        if (ln == 0) words[wv] = b;
        if (tid == 0) changed = 0;
        __syncthreads();
        u64 sup = 0;
        for (int w = 0; w <= wv; w++) {          // wv is wave-uniform
            u64 kw = words[w];
            if (w == wv) kw &= lowmask;
            sup |= row[w] & kw;
        }
        bool nk = valid && (sup == 0ull);
        if (nk != keep) changed = 1;
        keep = nk;
        __syncthreads();
        if (!changed) break;
    }
    if (tid < TOPK) {
        float x1 = boxK[tid * 4 + 0], y1 = boxK[tid * 4 + 1];
        float x2 = boxK[tid * 4 + 2], y2 = boxK[tid * 4 + 3];
        float sc = scoreK[tid];
        out[tid * 5 + 0] = keep ? x1 : 0.0f;
        out[tid * 5 + 1] = keep ? y1 : 0.0f;
        out[tid * 5 + 2] = keep ? x2 : 0.0f;
        out[tid * 5 + 3] = keep ? y2 : 0.0f;
        out[tid * 5 + 4] = keep ? sc : 0.0f;
    }
}

extern "C" void kernel_launch(void* const* d_in, const int* in_sizes, int n_in,
                              void* d_out, int out_size, void* d_ws, size_t ws_size,
                              hipStream_t stream) {
    const float* logits = (const float*)d_in[0];
    const float* boxes  = (const float*)d_in[1];
    float* out = (float*)d_out;
    int nrows = in_sizes[0] / N_CLS;   // 200000

    char* w = (char*)d_ws;
    unsigned* cnt    = (unsigned*)(w + OFF_CNT);
    unsigned* cnt2   = (unsigned*)(w + OFF_CNT2);
    unsigned* ghist  = (unsigned*)(w + OFF_GH);
    unsigned* rhist  = (unsigned*)(w + OFF_RH);
    u64* sorted      = (u64*)(w + OFF_SORTED);
    u64* sel         = (u64*)(w + OFF_SEL);
    u64* sel2        = (u64*)(w + OFF_SEL2);
    float* boxK      = (float*)(w + OFF_BOX);
    float* scoreK    = (float*)(w + OFF_SCORE);
    int* clsK        = (int*)(w + OFF_CLS);
    u64* mask        = (u64*)(w + OFF_MASK);

    hipMemsetAsync(w, 0, MEMSET_BYTES, stream);

    int nblk = (nrows + 255) / 256;
    k_pass1<<<nblk, 256, 0, stream>>>(logits, nrows, sel, cnt, ghist);
    k_refine<<<256, 256, 0, stream>>>(sel, cnt, ghist, rhist);
    k_select<<<256, 256, 0, stream>>>(sel, cnt, ghist, rhist, sel2, cnt2);
    k_rank<<<CAP2 / 256, 256, 0, stream>>>(sel2, cnt2, sorted);
    k_decode<<<(TOPK + 255) / 256, 256, 0, stream>>>(sorted, boxes, boxK, scoreK, clsK);
    k_conflict<<<(TOPK * 16 + 255) / 256, 256, 0, stream>>>(boxK, clsK, mask);
    k_nms_out<<<1, 1024, 0, stream>>>(mask, boxK, scoreK, out);
}

// Round 2
// 200.340 us; speedup vs baseline: 1.3628x; 1.3628x over previous
//
#include <hip/hip_runtime.h>
#include <stdint.h>
#include <math.h>

#define N_CLS    81
#define TOPK     1000
#define LISTCAP  (1u << 21)     // 2M candidate keys (16 MB)
#define CAP2     16384          // final selection capacity
#define SCORE_TH 0.05f
#define IMG_W    1333.0f
#define IMG_H    800.0f
#define GH_REP   8              // coarse-hist replicas (atomic spread)

// coarse bucket = float_bits >> 19, range for (0.05, 1.0] is [1961, 2032]
#define GH_BASE  1905           // ghist index = (bits>>19) - GH_BASE, in [56,127]

// workspace layout (byte offsets)
#define OFF_CNT    0                       // u32 total candidates
#define OFF_CNT2   8                       // u32 selected count
#define OFF_GH     64                      // u32[GH_REP][128] coarse hist (4096 B)
#define OFF_RH     4608                    // u32[1024] refined hist (4096 B)
#define OFF_SORTED 8704                    // u64[1000] sorted keys (0 sentinel)
#define MEMSET_BYTES 16704
#define OFF_SEL    16768                   // u64[LISTCAP]
#define OFF_SEL2   16793984                // u64[CAP2]
#define OFF_BOX    16925056                // f32[1000*4]
#define OFF_SCORE  16941056                // f32[1000]
#define OFF_CLS    16945056                // i32[1000]
#define OFF_MASK   16949056                // u64[1000*16] conflict bit matrix

#define ROWS_PER_BLK 128
#define TILE_FLOATS  (ROWS_PER_BLK * N_CLS)   // 10368 floats = 41472 B (16B-aligned)
#define CBUF_CAP     1024

typedef unsigned long long u64;

// direct global->LDS 16B DMA (m97 pattern): LDS dest = wave-uniform base + lane*16
__device__ __forceinline__ void gload_lds16(const float* g, float* l) {
    __builtin_amdgcn_global_load_lds(
        (const __attribute__((address_space(1))) unsigned int*)g,
        (__attribute__((address_space(3))) unsigned int*)l, 16, 0, 0);
}

// ------- K1: LDS-staged tile, pair-of-threads per row, 2 shuffles/row -------
// Thread h (=tid&1) of a pair owns classes c === h (mod 2). The softmax sum
// reproduces the EXACT fp association of the verified butterfly kernel:
// its tree = balanced tree over bit-reversed leaves t_l = e_l (+ e_{l+64}, l<17),
// top split = even/odd leaves -> per-thread 5-level bitrev subtree, then
// s = S_even + S_odd. max/exp/div are op-identical => bit-exact scores.
__global__ __launch_bounds__(256) void k_pass1(
        const float* __restrict__ logits, int nrows,
        u64* __restrict__ sel, unsigned* __restrict__ cnt,
        unsigned* __restrict__ ghist) {
    __shared__ float tile[TILE_FLOATS];
    __shared__ unsigned lh[128];
    __shared__ u64 cbuf[CBUF_CAP];
    __shared__ unsigned lcnt, gbase;
    int tid = threadIdx.x, wv = tid >> 6, ln = tid & 63;
    for (int i = tid; i < 128; i += 256) lh[i] = 0;
    if (tid == 0) lcnt = 0;

    int base = blockIdx.x * ROWS_PER_BLK;
    int nr = nrows - base; if (nr > ROWS_PER_BLK) nr = ROWS_PER_BLK;
    const float* gtile = logits + (size_t)base * N_CLS;

    if (nr == ROWS_PER_BLK) {
        // 10 iterations x 4 waves x 1KB = 40960 B coalesced direct-to-LDS
        #pragma unroll
        for (int it = 0; it < 10; ++it) {
            int c = it * 1024 + wv * 256;          // float offset, wave-uniform
            gload_lds16(gtile + c + ln * 4, tile + c);
        }
        // tail 128 floats (40960..41472 B)
        if (tid < TILE_FLOATS - 10240) tile[10240 + tid] = gtile[10240 + tid];
    } else {
        for (int i = tid; i < nr * N_CLS; i += 256) tile[i] = gtile[i];
    }
    __syncthreads();   // drains vmcnt (global_load_lds) + lgkmcnt

    int r = tid >> 1, h = tid & 1;
    if (r < nr) {
        const int rb = r * N_CLS + h;              // first owned class in LDS
        float v[41];
        #pragma unroll
        for (int m = 0; m < 40; ++m) v[m] = tile[rb + 2 * m];
        v[40] = (h == 0) ? tile[rb + 80] : 0.0f;   // class 80 only exists for h=0

        // ---- row max (exact, order-free) ----
        float mx = v[0];
        #pragma unroll
        for (int m = 1; m < 40; ++m) mx = fmaxf(mx, v[m]);
        mx = fmaxf(mx, (h == 0) ? v[40] : v[0]);
        float om = __shfl_xor(mx, 1);
        float mrow = fmaxf(mx, om);

        // ---- exps (op-identical to reference kernel) ----
        #pragma unroll
        for (int m = 0; m < 40; ++m) v[m] = expf(v[m] - mrow);
        v[40] = (h == 0) ? expf(v[40] - mrow) : 0.0f;

        // ---- per-thread bitrev subtree over leaves l = h + 2*b ----
        // leaf t_l = e_l + e_{l+64} for l<17 (b<8 both h; b==8 only h==0)
        float stk0 = 0.f, stk1 = 0.f, stk2 = 0.f, stk3 = 0.f, stk4 = 0.f;
        float S = 0.f;
        #pragma unroll
        for (int i = 0; i < 32; ++i) {
            const int b = ((i & 1) << 4) | ((i & 2) << 2) | (i & 4) |
                          ((i & 8) >> 2) | ((i & 16) >> 4);   // bitrev5(i)
            float x = v[b];
            if (b < 8) x += v[b + 32];
            else if (b == 8) x = (h == 0) ? x + v[40] : x;
            if (i & 1) { x = stk0 + x;
              if (i & 2) { x = stk1 + x;
                if (i & 4) { x = stk2 + x;
                  if (i & 8) { x = stk3 + x;
                    if (i & 16) { S = stk4 + x; } else stk4 = x;
                  } else stk3 = x;
                } else stk2 = x;
              } else stk1 = x;
            } else stk0 = x;
        }
        float oS = __shfl_xor(S, 1);
        float s = (h == 0) ? (S + oS) : (oS + S);  // exact top-level association

        // ---- emit: conservative pre-filter, then bit-exact p>0.05 ----
        float eth = 0.0499f * s;                   // 0.2% margin >> fp rounding
        unsigned rowflat = (unsigned)(base + r) * N_CLS + (unsigned)h;
        #pragma unroll
        for (int m = 0; m < 41; ++m) {
            float e = v[m];
            if ((m + h) != 0 && e > eth) {         // skip background (h=0,m=0)
                float p = e / s;                   // identical division
                if (p > SCORE_TH) {
                    unsigned fb = __float_as_uint(p);
                    atomicAdd(&lh[(fb >> 19) - GH_BASE], 1u);
                    unsigned flat = rowflat + 2u * (unsigned)m;
                    u64 key = ((u64)fb << 32) | (u64)(0xFFFFFFu - flat);
                    unsigned pos = atomicAdd(&lcnt, 1u);
                    if (pos < CBUF_CAP) cbuf[pos] = key;
                    else { unsigned gp = atomicAdd(cnt, 1u); if (gp < LISTCAP) sel[gp] = key; }
                }
            }
        }
    }
    __syncthreads();
    unsigned* gh = ghist + (blockIdx.x & (GH_REP - 1)) * 128;
    for (int i = tid; i < 128; i += 256) {
        unsigned vv = lh[i];
        if (vv) atomicAdd(&gh[i], vv);
    }
    unsigned total = lcnt; if (total > CBUF_CAP) total = CBUF_CAP;
    if (tid == 0) gbase = atomicAdd(cnt, total);
    __syncthreads();
    unsigned gb = gbase;
    for (unsigned i = tid; i < total; i += 256) {
        unsigned gp = gb + i;
        if (gp < LISTCAP) sel[gp] = cbuf[i];
    }
}

// find coarse bucket B (ghist idx) containing rank TOPK; returns -1 if total<TOPK.
// *c_above = count strictly above bucket B.
__device__ inline int scan_coarse(const unsigned* __restrict__ ghist, unsigned* c_above) {
    unsigned cum = 0;
    for (int i = 127; i >= 0; --i) {
        unsigned c = 0;
        #pragma unroll
        for (int r = 0; r < GH_REP; r++) c += ghist[r * 128 + i];
        if (cum + c >= TOPK) { *c_above = cum; return i; }
        cum += c;
    }
    *c_above = cum;
    return -1;
}

// ------- K2: refined 1024-bin hist (shift 9) inside the coarse bucket -------
__global__ __launch_bounds__(256) void k_refine(
        const u64* __restrict__ sel, const unsigned* __restrict__ cnt,
        const unsigned* __restrict__ ghist, unsigned* __restrict__ rhist) {
    __shared__ unsigned lh[1024];
    __shared__ int sB;
    int tid = threadIdx.x;
    for (int i = tid; i < 1024; i += 256) lh[i] = 0;
    if (tid == 0) { unsigned ca; sB = scan_coarse(ghist, &ca); }
    __syncthreads();
    int B = sB;
    if (B < 0) return;   // fewer than TOPK candidates total
    unsigned Bbits = (unsigned)(B + GH_BASE);
    unsigned M = *cnt; if (M > LISTCAP) M = LISTCAP;
    unsigned stride = gridDim.x * blockDim.x;
    for (unsigned i = blockIdx.x * blockDim.x + tid; i < M; i += stride) {
        unsigned bits = (unsigned)(sel[i] >> 32);
        if ((bits >> 19) == Bbits) atomicAdd(&lh[(bits >> 9) & 1023u], 1u);
    }
    __syncthreads();
    for (int i = tid; i < 1024; i += 256) {
        unsigned v = lh[i];
        if (v) atomicAdd(&rhist[i], v);
    }
}

// ------- K3: compute exact threshold tb, compact keys >= tb into sel2 -------
__global__ __launch_bounds__(256) void k_select(
        const u64* __restrict__ sel, const unsigned* __restrict__ cnt,
        const unsigned* __restrict__ ghist, const unsigned* __restrict__ rhist,
        u64* __restrict__ sel2, unsigned* __restrict__ cnt2) {
    __shared__ unsigned s4[256];
    __shared__ unsigned tbs;
    int tid = threadIdx.x, ln = tid & 63;
    unsigned ps = 0;
    #pragma unroll
    for (int k = 0; k < 4; k++) ps += rhist[tid * 4 + k];
    s4[tid] = ps;
    __syncthreads();
    if (tid == 0) {
        unsigned c_above;
        int B = scan_coarse(ghist, &c_above);
        unsigned tb = 0;
        if (B >= 0) {
            unsigned cab = c_above;
            int g = -1;
            for (int i = 255; i >= 0; --i) {
                if (cab + s4[i] >= TOPK) { g = i; break; }
                cab += s4[i];
            }
            int sb = 0;
            if (g >= 0) {
                for (int i = g * 4 + 3; i >= g * 4; --i) {
                    unsigned c = rhist[i];
                    if (cab + c >= TOPK) { sb = i; break; }
                    cab += c;
                }
            }
            tb = ((unsigned)(B + GH_BASE) << 19) | ((unsigned)sb << 9);
        }
        tbs = tb;
    }
    __syncthreads();
    unsigned tb = tbs;
    unsigned M = *cnt; if (M > LISTCAP) M = LISTCAP;
    unsigned stride = gridDim.x * blockDim.x;
    for (unsigned ibase = blockIdx.x * blockDim.x; ibase < M; ibase += stride) {
        unsigned i = ibase + tid;
        bool act = (i < M);
        u64 key = act ? sel[i] : 0ull;
        bool c = act && ((unsigned)(key >> 32) >= tb);
        u64 b = __ballot(c);
        int n = __popcll(b);
        if (n == 0) continue;
        unsigned wb = 0;
        if (ln == 0) wb = atomicAdd(cnt2, (unsigned)n);
        wb = __shfl(wb, 0);
        if (c) {
            unsigned pos = wb + (unsigned)__popcll(b & ((1ull << ln) - 1ull));
            if (pos < CAP2) sel2[pos] = key;
        }
    }
}

// ------- K4: exact rank by counting (keys distinct), scatter to sorted -------
__global__ __launch_bounds__(256) void k_rank(
        const u64* __restrict__ sel2, const unsigned* __restrict__ cnt2,
        u64* __restrict__ sorted) {
    __shared__ u64 ch[2048];
    unsigned S = *cnt2; if (S > CAP2) S = CAP2;
    if (blockIdx.x * 256u >= S) return;
    unsigned t = blockIdx.x * 256u + threadIdx.x;
    u64 my = (t < S) ? sel2[t] : 0ull;
    int r = 0;
    for (unsigned c0 = 0; c0 < S; c0 += 2048) {
        unsigned n = S - c0; if (n > 2048) n = 2048;
        __syncthreads();
        for (unsigned i = threadIdx.x; i < n; i += 256) ch[i] = sel2[c0 + i];
        __syncthreads();
        if (t < S)
            for (unsigned j = 0; j < n; j++) r += (ch[j] > my) ? 1 : 0;
    }
    if (t < S && r < TOPK) sorted[r] = my;
}

// ------- K5: decode keys, gather + clip boxes -------
__global__ __launch_bounds__(256) void k_decode(
        const u64* __restrict__ sorted, const float* __restrict__ boxes,
        float* __restrict__ boxK, float* __restrict__ scoreK, int* __restrict__ clsK) {
    int t = blockIdx.x * blockDim.x + threadIdx.x;
    if (t >= TOPK) return;
    u64 key = sorted[t];
    if (key != 0ull) {
        float sc = __uint_as_float((unsigned)(key >> 32));
        unsigned fi = 0xFFFFFFu - (unsigned)(key & 0xFFFFFFFFull);
        unsigned prop = fi / N_CLS;
        int cls = (int)(fi - prop * N_CLS);
        const float* b = boxes + (size_t)prop * 4;
        boxK[t * 4 + 0] = fminf(fmaxf(b[0], 0.0f), IMG_W - 1.0f);
        boxK[t * 4 + 1] = fminf(fmaxf(b[1], 0.0f), IMG_H - 1.0f);
        boxK[t * 4 + 2] = fminf(fmaxf(b[2], 0.0f), IMG_W - 1.0f);
        boxK[t * 4 + 3] = fminf(fmaxf(b[3], 0.0f), IMG_H - 1.0f);
        scoreK[t] = sc;
        clsK[t] = cls;
    } else {
        boxK[t * 4 + 0] = 0.0f; boxK[t * 4 + 1] = 0.0f;
        boxK[t * 4 + 2] = 0.0f; boxK[t * 4 + 3] = 0.0f;
        scoreK[t] = 0.0f;
        clsK[t] = -1;
    }
}

// ------- K6: conflict bit-matrix (IoU > 0.5 && same class) -------
__global__ __launch_bounds__(256) void k_conflict(
        const float* __restrict__ boxK, const int* __restrict__ clsK,
        u64* __restrict__ mask) {
    int t = blockIdx.x * blockDim.x + threadIdx.x;
    if (t >= TOPK * 16) return;
    int i = t >> 4, w = t & 15;
    float x1 = boxK[i * 4 + 0], y1 = boxK[i * 4 + 1];
    float x2 = boxK[i * 4 + 2], y2 = boxK[i * 4 + 3];
    int ci = clsK[i];
    float ai = (x2 - x1) * (y2 - y1);
    u64 m = 0;
    int jbase = w << 6;
    for (int jj = 0; jj < 64; jj++) {
        int j = jbase + jj;
        if (j >= TOPK) break;
        float u1 = boxK[j * 4 + 0], w1 = boxK[j * 4 + 1];
        float u2 = boxK[j * 4 + 2], w2 = boxK[j * 4 + 3];
        float aj = (u2 - u1) * (w2 - w1);
        float ww = fmaxf(fminf(x2, u2) - fmaxf(x1, u1), 0.0f);
        float hh = fmaxf(fminf(y2, w2) - fmaxf(y1, w1), 0.0f);
        float inter = ww * hh;
        float iou = inter / (ai + aj - inter + 1e-9f);
        if (iou > 0.5f && ci == clsK[j]) m |= (1ull << jj);
    }
    mask[(size_t)i * 16 + w] = m;
}

// ------- K7: Jacobi fixed-point of the triangular greedy-NMS recurrence -------
// keep[i] = valid[i] & !OR_{j<i}(keep[j] & conflict[j][i]); unique fixed point.
__global__ __launch_bounds__(1024) void k_nms_out(
        const u64* __restrict__ mask, const float* __restrict__ boxK,
        const float* __restrict__ scoreK, float* __restrict__ out) {
    __shared__ u64 words[16];
    __shared__ int changed;
    int tid = threadIdx.x, wv = tid >> 6, ln = tid & 63;
    bool valid = (tid < TOPK) && (scoreK[tid] > 0.0f);
    u64 row[16];
    #pragma unroll
    for (int w = 0; w < 16; w++)
        row[w] = (tid < TOPK) ? mask[(size_t)tid * 16 + w] : 0ull;
    u64 lowmask = (1ull << ln) - 1ull;
    bool keep = valid;
    for (int it = 0; it < 1024; ++it) {
        u64 b = __ballot(keep);
        if (ln == 0) words[wv] = b;
        if (tid == 0) changed = 0;
        __syncthreads();
        u64 sup = 0;
        for (int w = 0; w <= wv; w++) {          // wv is wave-uniform
            u64 kw = words[w];
            if (w == wv) kw &= lowmask;
            sup |= row[w] & kw;
        }
        bool nk = valid && (sup == 0ull);
        if (nk != keep) changed = 1;
        keep = nk;
        __syncthreads();
        if (!changed) break;
    }
    if (tid < TOPK) {
        float x1 = boxK[tid * 4 + 0], y1 = boxK[tid * 4 + 1];
        float x2 = boxK[tid * 4 + 2], y2 = boxK[tid * 4 + 3];
        float sc = scoreK[tid];
        out[tid * 5 + 0] = keep ? x1 : 0.0f;
        out[tid * 5 + 1] = keep ? y1 : 0.0f;
        out[tid * 5 + 2] = keep ? x2 : 0.0f;
        out[tid * 5 + 3] = keep ? y2 : 0.0f;
        out[tid * 5 + 4] = keep ? sc : 0.0f;
    }
}

extern "C" void kernel_launch(void* const* d_in, const int* in_sizes, int n_in,
                              void* d_out, int out_size, void* d_ws, size_t ws_size,
                              hipStream_t stream) {
    const float* logits = (const float*)d_in[0];
    const float* boxes  = (const float*)d_in[1];
    float* out = (float*)d_out;
    int nrows = in_sizes[0] / N_CLS;   // 200000

    char* w = (char*)d_ws;
    unsigned* cnt    = (unsigned*)(w + OFF_CNT);
    unsigned* cnt2   = (unsigned*)(w + OFF_CNT2);
    unsigned* ghist  = (unsigned*)(w + OFF_GH);
    unsigned* rhist  = (unsigned*)(w + OFF_RH);
    u64* sorted      = (u64*)(w + OFF_SORTED);
    u64* sel         = (u64*)(w + OFF_SEL);
    u64* sel2        = (u64*)(w + OFF_SEL2);
    float* boxK      = (float*)(w + OFF_BOX);
    float* scoreK    = (float*)(w + OFF_SCORE);
    int* clsK        = (int*)(w + OFF_CLS);
    u64* mask        = (u64*)(w + OFF_MASK);

    hipMemsetAsync(w, 0, MEMSET_BYTES, stream);

    int nblk = (nrows + ROWS_PER_BLK - 1) / ROWS_PER_BLK;
    k_pass1<<<nblk, 256, 0, stream>>>(logits, nrows, sel, cnt, ghist);
    k_refine<<<256, 256, 0, stream>>>(sel, cnt, ghist, rhist);
    k_select<<<256, 256, 0, stream>>>(sel, cnt, ghist, rhist, sel2, cnt2);
    k_rank<<<CAP2 / 256, 256, 0, stream>>>(sel2, cnt2, sorted);
    k_decode<<<(TOPK + 255) / 256, 256, 0, stream>>>(sorted, boxes, boxK, scoreK, clsK);
    k_conflict<<<(TOPK * 16 + 255) / 256, 256, 0, stream>>>(boxK, clsK, mask);
    k_nms_out<<<1, 1024, 0, stream>>>(mask, boxK, scoreK, out);
}